// Round 14
// baseline (230.617 us; speedup 1.0000x reference)
//
#include <hip/hip_runtime.h>
#include <stdint.h>

#define S_LEN 2048
#define HID   2048
#define NH    32
#define NKV   8
#define HD    64
#define BATCH 2
#define NROWS (BATCH * S_LEN)      // 4096
#define QKVN  (NH*HD + 2*NKV*HD)   // 3072

typedef unsigned short u16;
typedef __bf16 bf16_t;
typedef bf16_t bf16x8 __attribute__((ext_vector_type(8)));
typedef float  f32x4  __attribute__((ext_vector_type(4)));
typedef float  f32x16 __attribute__((ext_vector_type(16)));
typedef u16    u16x8  __attribute__((ext_vector_type(8)));

#define LOG2E 1.4426950408889634f

__device__ __forceinline__ u16 f2bf(float f) {
    union { float f; uint32_t u; } v; v.f = f;
    uint32_t u = v.u;
    return (u16)((u + 0x7fffu + ((u >> 16) & 1u)) >> 16);
}

__device__ __forceinline__ unsigned cvtpk(float a, float b) {
    unsigned r;
    asm("v_cvt_pk_bf16_f32 %0, %1, %2" : "=v"(r) : "v"(a), "v"(b));
    return r;
}

// v_permlane32_swap_b32 a, b:  a'[l>=32] = b[l-32];  b'[l<32] = a[l+32]  (HW-verified R5)
__device__ __forceinline__ void plswap(unsigned &a, unsigned &b) {
    asm volatile("v_permlane32_swap_b32 %0, %1" : "+v"(a), "+v"(b));
}

__device__ __forceinline__ void llds16(const void* g, void* l) {
    __builtin_amdgcn_global_load_lds(
        (const __attribute__((address_space(1))) void*)g,
        (__attribute__((address_space(3))) void*)l,
        16, 0, 0);
}

// 64B-row chunk swizzle: uniform 8-slot spread (R11-verified, 0 conflicts).
__device__ __forceinline__ unsigned swz(unsigned row) {
    return ((row ^ (row >> 2)) & 3u) << 4;
}

#define SB()    __builtin_amdgcn_sched_barrier(0)
#define BAR()   __builtin_amdgcn_s_barrier()

// counted-vmcnt barrier (attn): wait for all but N newest VMEM ops, then raw barrier.
#define CBAR(N) do { \
    asm volatile("s_waitcnt vmcnt(" #N ")" ::: "memory"); \
    __builtin_amdgcn_s_barrier(); \
    __builtin_amdgcn_sched_barrier(0); \
} while (0)

// ---------------- fused prep: f32->bf16 convert (5 tensors) + RoPE table + bias concat ----------------
#define CVT_GROUPS 2359296            // 8-elem groups across x|Wq|Wk|Wv|Wo
__global__ void prep_all(const float* __restrict__ x, const float* __restrict__ wq,
                         const float* __restrict__ wk, const float* __restrict__ wv,
                         const float* __restrict__ wo,
                         const float* __restrict__ bq, const float* __restrict__ bk,
                         const float* __restrict__ bv,
                         u16* __restrict__ xb, u16* __restrict__ wqkvb, u16* __restrict__ wob,
                         float* __restrict__ rtab, float* __restrict__ bqkv) {
    int e = blockIdx.x * 256 + threadIdx.x;
    if (e < CVT_GROUPS) {
        const float* s; u16* d; int o;
        if (e < 1048576)      { s = x;  d = xb;                 o = e; }
        else if (e < 1572864) { s = wq; d = wqkvb;              o = e - 1048576; }
        else if (e < 1703936) { s = wk; d = wqkvb + 2048*2048;  o = e - 1572864; }
        else if (e < 1835008) { s = wv; d = wqkvb + 2560*2048;  o = e - 1703936; }
        else                  { s = wo; d = wob;                o = e - 1835008; }
        const float4* sp = (const float4*)s;
        float4 a = sp[2*(size_t)o], b = sp[2*(size_t)o + 1];
        u16x8 r;
        r[0]=f2bf(a.x); r[1]=f2bf(a.y); r[2]=f2bf(a.z); r[3]=f2bf(a.w);
        r[4]=f2bf(b.x); r[5]=f2bf(b.y); r[6]=f2bf(b.z); r[7]=f2bf(b.w);
        *(u16x8*)(d + 8*(size_t)o) = r;
    } else if (e < CVT_GROUPS + 65536) {
        int idx = e - CVT_GROUPS;          // s*32 + i
        int i = idx & 31, s = idx >> 5;
        float invf = exp2f(-(float)i * (13.287712379549449f / 32.0f));
        float ang = (float)s * invf;
        float sn, cs;
        sincosf(ang, &sn, &cs);
        rtab[idx] = cs;
        rtab[S_LEN*32 + idx] = sn;
    } else if (e < CVT_GROUPS + 65536 + QKVN) {
        int i = e - CVT_GROUPS - 65536;
        bqkv[i] = (i < 2048) ? bq[i] : (i < 2560 ? bk[i - 2048] : bv[i - 2560]);
    }
}

// =====================================================================================
// GEMM (R14): BARRIER-FREE self-synced pipeline. Block 128x128, 4 waves (2x2),
// wave tile 64x64, BK=32, 32x32x16 MFMA. Every LDS region is PRIVATE to one wave
// (A-half 4KB + B-half 4KB per buf, 2 bufs = 16KB/wave, 64KB/block): the wave
// stages its own operands with 8 llds16 and self-syncs with its own vmcnt/lgkm
// counters. No s_barrier anywhere -> waves drift freely, LDS-port and MFMA bursts
// interleave across the 8 resident waves instead of phase-locking.
//   per iter kt: vmcnt(8) [stage(kt) landed; stage(kt+1) in flight]
//                -> 8 ds_reads (A4,B0x2,B1x2) -> lgkm(2) -> 4 MFMA
//                -> lgkm(0) -> issue stage(kt+2) into buf[kt&1] -> 4 MFMA
// =====================================================================================

// ---------------- QKV GEMM + fused RoPE/scale/pack epilogue ----------------
__global__ __launch_bounds__(256, 2) void gemm_qkv(
    const u16* __restrict__ A, const u16* __restrict__ Bw,
    const float* __restrict__ bias, const float* __restrict__ rtab,
    const float* __restrict__ kw,
    u16* __restrict__ qpk, u16* __restrict__ kpk, u16* __restrict__ vlin)
{
    const int K = HID;
    const int nbn = QKVN >> 7;              // 24
    const int nwg = (NROWS >> 7) * nbn;     // 768
    int wg = blockIdx.x;
    wg = (wg & 7) * (nwg >> 3) + (wg >> 3); // XCD -> contiguous chunk
    const int bm = wg / nbn, bn = wg % nbn;
    const int brow = bm << 7, bcol = bn << 7;

    __shared__ u16 sbuf[2][4][4096];        // [buf][wave][A 2048 | B 2048] u16 = 64 KB

    const int t = threadIdx.x;
    const int lane = t & 63, wid = t >> 6;
    const int wm = wid >> 1, wn = wid & 1;
    const int lq = lane & 31, hi = lane >> 5;

    const int arow0 = brow + wm*64;         // wave's 64 A rows
    const int brow0 = bcol + wn*64;         // wave's 64 B rows (C cols)
    const unsigned rl = ((unsigned)lane) >> 2;        // 0..15 row-in-group
    const unsigned cb = ((unsigned)lane & 3) << 4;    // 16B chunk in 64B row

    auto stage = [&](int kt, int bi) {      // 8 llds16, all into THIS wave's region
        const int k0 = kt << 5;
        u16* wb = &sbuf[bi][wid][0];
        #pragma unroll
        for (int i = 0; i < 4; ++i) {
            const unsigned r = i*16 + rl;
            const unsigned scb = cb ^ swz(r);
            llds16(A + (size_t)(arow0 + r) * K + (k0 + (scb >> 1)), wb + ((i*1024 + lane*16) >> 1));
        }
        #pragma unroll
        for (int i = 0; i < 4; ++i) {
            const unsigned r = i*16 + rl;
            const unsigned scb = cb ^ swz(r);
            llds16(Bw + (size_t)(brow0 + r) * K + (k0 + (scb >> 1)), wb + 2048 + ((i*1024 + lane*16) >> 1));
        }
    };

    f32x16 acc[2][2] = {};
    const int nk = K >> 5;                  // 64

    stage(0, 0);
    stage(1, 1);
    for (int kt = 0; kt < nk; ++kt) {
        if (kt + 1 < nk) asm volatile("s_waitcnt vmcnt(8)" ::: "memory");
        else             asm volatile("s_waitcnt vmcnt(0)" ::: "memory");
        SB();
        const char* sA = (const char*)&sbuf[kt & 1][wid][0];
        const char* sB = sA + 4096;
        bf16x8 af[4], bfv[4];
        #pragma unroll
        for (int mt = 0; mt < 2; ++mt)
            #pragma unroll
            for (int s = 0; s < 2; ++s) {
                const unsigned row = mt*32 + lq;
                af[mt*2+s] = *(const bf16x8*)(sA + row*64 + ((unsigned)(32*s + 16*hi) ^ swz(row)));
            }
        #pragma unroll
        for (int s = 0; s < 2; ++s) {
            const unsigned row = lq;
            bfv[s] = *(const bf16x8*)(sB + row*64 + ((unsigned)(32*s + 16*hi) ^ swz(row)));
        }
        #pragma unroll
        for (int s = 0; s < 2; ++s) {
            const unsigned row = 32 + lq;
            bfv[2+s] = *(const bf16x8*)(sB + row*64 + ((unsigned)(32*s + 16*hi) ^ swz(row)));
        }
        SB();
        asm volatile("s_waitcnt lgkmcnt(2)" ::: "memory");
        SB();
        __builtin_amdgcn_s_setprio(1);
        #pragma unroll
        for (int mt = 0; mt < 2; ++mt)
            #pragma unroll
            for (int s = 0; s < 2; ++s)
                acc[mt][0] = __builtin_amdgcn_mfma_f32_32x32x16_bf16(af[mt*2+s], bfv[s], acc[mt][0], 0, 0, 0);
        __builtin_amdgcn_s_setprio(0);
        asm volatile("s_waitcnt lgkmcnt(0)" ::: "memory");
        SB();
        if (kt + 2 < nk) stage(kt + 2, kt & 1);   // own region, reads already done
        __builtin_amdgcn_s_setprio(1);
        #pragma unroll
        for (int mt = 0; mt < 2; ++mt)
            #pragma unroll
            for (int s = 0; s < 2; ++s)
                acc[mt][1] = __builtin_amdgcn_mfma_f32_32x32x16_bf16(af[mt*2+s], bfv[2+s], acc[mt][1], 0, 0, 0);
        __builtin_amdgcn_s_setprio(0);
    }

    const int rowb = brow + wm*64;
    const int c64 = bcol + wn*64;           // this wave's 64-col head block
    const int hb  = c64 >> 6;               // 0..47: <32 Q, <40 K, else V
    if (hb < 40) {
        const bool isQ = hb < 32;
        const float sc = isQ ? (0.125f * LOG2E * kw[hb]) : 1.0f;
        u16* dst = isQ ? qpk : kpk;
        const int nheads = isQ ? 32 : 8;
        const int hloc = isQ ? hb : (hb - 32);
        const float b1 = bias[c64 + lq];
        const float b2 = bias[c64 + 32 + lq];
        #pragma unroll
        for (int mt = 0; mt < 2; ++mt) {
            #pragma unroll
            for (int r = 0; r < 16; ++r) {
                const int row = rowb + mt*32 + (r & 3) + 8*(r >> 2) + 4*hi;
                const int s = row & (S_LEN - 1);
                const int bb = row >> 11;
                const float x1 = acc[mt][0][r] + b1;
                const float x2 = acc[mt][1][r] + b2;
                const float c = rtab[s*32 + lq];
                const float sn = rtab[S_LEN*32 + s*32 + lq];
                const size_t base = ((size_t)(bb*nheads + hloc)) * (S_LEN*64) + (size_t)s*64;
                dst[base + lq]      = f2bf((x1*c - x2*sn) * sc);
                dst[base + lq + 32] = f2bf((x2*c + x1*sn) * sc);
            }
        }
    } else {
        #pragma unroll
        for (int nt = 0; nt < 2; ++nt) {
            const int col = c64 + nt*32 + lq;
            const float bv = bias[col];
            #pragma unroll
            for (int mt = 0; mt < 2; ++mt)
                #pragma unroll
                for (int r = 0; r < 16; ++r) {
                    const int row = rowb + mt*32 + (r & 3) + 8*(r >> 2) + 4*hi;
                    vlin[(size_t)row * 512 + (col - 2560)] = f2bf(acc[mt][nt][r] + bv);
                }
        }
    }
}

// ---------------- o-proj GEMM, C[M][N] = A @ Bw^T + bias (f32 out) ----------------
__global__ __launch_bounds__(256, 2) void gemm_bt(
    const u16* __restrict__ A, const u16* __restrict__ Bw,
    const float* __restrict__ bias, float* __restrict__ C,
    int M, int N, int K)
{
    const int nbn = N >> 7;                 // 16
    const int nwg = (M >> 7) * nbn;         // 512
    int wg = blockIdx.x;
    wg = (wg & 7) * (nwg >> 3) + (wg >> 3);
    const int bm = wg / nbn, bn = wg % nbn;
    const int brow = bm << 7, bcol = bn << 7;

    __shared__ u16 sbuf[2][4][4096];

    const int t = threadIdx.x;
    const int lane = t & 63, wid = t >> 6;
    const int wm = wid >> 1, wn = wid & 1;
    const int lq = lane & 31, hi = lane >> 5;

    const int arow0 = brow + wm*64;
    const int brow0 = bcol + wn*64;
    const unsigned rl = ((unsigned)lane) >> 2;
    const unsigned cb = ((unsigned)lane & 3) << 4;

    auto stage = [&](int kt, int bi) {
        const int k0 = kt << 5;
        u16* wb = &sbuf[bi][wid][0];
        #pragma unroll
        for (int i = 0; i < 4; ++i) {
            const unsigned r = i*16 + rl;
            const unsigned scb = cb ^ swz(r);
            llds16(A + (size_t)(arow0 + r) * K + (k0 + (scb >> 1)), wb + ((i*1024 + lane*16) >> 1));
        }
        #pragma unroll
        for (int i = 0; i < 4; ++i) {
            const unsigned r = i*16 + rl;
            const unsigned scb = cb ^ swz(r);
            llds16(Bw + (size_t)(brow0 + r) * K + (k0 + (scb >> 1)), wb + 2048 + ((i*1024 + lane*16) >> 1));
        }
    };

    f32x16 acc[2][2] = {};
    const int nk = K >> 5;

    stage(0, 0);
    stage(1, 1);
    for (int kt = 0; kt < nk; ++kt) {
        if (kt + 1 < nk) asm volatile("s_waitcnt vmcnt(8)" ::: "memory");
        else             asm volatile("s_waitcnt vmcnt(0)" ::: "memory");
        SB();
        const char* sA = (const char*)&sbuf[kt & 1][wid][0];
        const char* sB = sA + 4096;
        bf16x8 af[4], bfv[4];
        #pragma unroll
        for (int mt = 0; mt < 2; ++mt)
            #pragma unroll
            for (int s = 0; s < 2; ++s) {
                const unsigned row = mt*32 + lq;
                af[mt*2+s] = *(const bf16x8*)(sA + row*64 + ((unsigned)(32*s + 16*hi) ^ swz(row)));
            }
        #pragma unroll
        for (int s = 0; s < 2; ++s) {
            const unsigned row = lq;
            bfv[s] = *(const bf16x8*)(sB + row*64 + ((unsigned)(32*s + 16*hi) ^ swz(row)));
        }
        #pragma unroll
        for (int s = 0; s < 2; ++s) {
            const unsigned row = 32 + lq;
            bfv[2+s] = *(const bf16x8*)(sB + row*64 + ((unsigned)(32*s + 16*hi) ^ swz(row)));
        }
        SB();
        asm volatile("s_waitcnt lgkmcnt(2)" ::: "memory");
        SB();
        __builtin_amdgcn_s_setprio(1);
        #pragma unroll
        for (int mt = 0; mt < 2; ++mt)
            #pragma unroll
            for (int s = 0; s < 2; ++s)
                acc[mt][0] = __builtin_amdgcn_mfma_f32_32x32x16_bf16(af[mt*2+s], bfv[s], acc[mt][0], 0, 0, 0);
        __builtin_amdgcn_s_setprio(0);
        asm volatile("s_waitcnt lgkmcnt(0)" ::: "memory");
        SB();
        if (kt + 2 < nk) stage(kt + 2, kt & 1);
        __builtin_amdgcn_s_setprio(1);
        #pragma unroll
        for (int mt = 0; mt < 2; ++mt)
            #pragma unroll
            for (int s = 0; s < 2; ++s)
                acc[mt][1] = __builtin_amdgcn_mfma_f32_32x32x16_bf16(af[mt*2+s], bfv[2+s], acc[mt][1], 0, 0, 0);
        __builtin_amdgcn_s_setprio(0);
    }

    #pragma unroll
    for (int mt = 0; mt < 2; ++mt)
        #pragma unroll
        for (int nt = 0; nt < 2; ++nt) {
            const int col = bcol + wn*64 + nt*32 + lq;
            const float bv = bias[col];
            #pragma unroll
            for (int r = 0; r < 16; ++r) {
                const int row = brow + wm*64 + mt*32 + (r & 3) + 8*(r >> 2) + 4*hi;
                C[(size_t)row * N + col] = acc[mt][nt][r] + bv;
            }
        }
}

// ---------------- pack V transposed: bf16 vlin[row][512] -> vtb[b*8+kvh][64][S] ----------------
__global__ void pack_vt(const u16* __restrict__ vlin, u16* __restrict__ vtb) {
    __shared__ u16 tile[64][67];
    const int st = blockIdx.x;          // s-tile
    const int bk = blockIdx.y;          // b*8 + kvh
    const int t = threadIdx.x;
    const int b = bk >> 3, kvh = bk & 7;
    const int r = t >> 2, cg = (t & 3) << 4;
    const u16* src = vlin + ((size_t)(b*S_LEN + st*64 + r)) * 512 + kvh*64 + cg;
    #pragma unroll
    for (int j = 0; j < 16; ++j) tile[r][cg + j] = src[j];
    __syncthreads();
    const int d = t >> 2, sg = (t & 3) << 4;
    u16* dst = vtb + ((size_t)(bk*64 + d)) * S_LEN + st*64 + sg;
    #pragma unroll
    for (int j = 0; j < 16; ++j) dst[j] = tile[sg + j][d];
}

// ---------------- flash attention: 8 waves x 32 q-rows, swapped 32x32 MFMA ----------------
__global__ __launch_bounds__(512, 4) void attn_fwd(
    const u16* __restrict__ Q,      // [B*NH][S][64] packed, scaled
    const u16* __restrict__ Kk,     // [B*NKV][S][64]
    const u16* __restrict__ Vt,     // [B*NKV][64][S]
    u16* __restrict__ O)            // [B*S][NH*64]
{
    __shared__ u16 sK[3][64 * 64];
    __shared__ u16 sV[3][64 * 64];

    const int t = threadIdx.x;
    const int lane = t & 63, wid = t >> 6;
    const int hi = lane >> 5, lq = lane & 31;
    const int bid = blockIdx.x;
    const int qb = (bid < 256) ? (7 - (bid >> 6)) : ((bid >> 6) - 4);
    const int bh = bid & 63;
    const int b = bh >> 5, h = bh & 31;
    const int kvh = h >> 2;

    const u16* Kp = Kk + ((size_t)(b*NKV + kvh)) * (S_LEN * 64);
    const u16* Vp = Vt + ((size_t)(b*NKV + kvh)) * (64 * S_LEN);

    const int q0w = qb*256 + wid*32;
    const int qg  = q0w + lq;

    const u16* Qrow = Q + (((size_t)bh) * S_LEN + qg) * 64 + 8*hi;
    bf16x8 qf[4];
    #pragma unroll
    for (int kd = 0; kd < 4; ++kd)
        qf[kd] = *(const bf16x8*)(Qrow + 16*kd);

    f32x16 accO0 = {}, accO1 = {};
    float m_run = 0.f, l_run = 0.f;

    const int ntB = 4*qb + 4;
    const int tmax_w = (q0w + 31) >> 6;

    auto stageKV = [&](int kt, int bi) {
        const int kv = kt << 6;
        const unsigned row = t >> 3, cb = (t & 7) << 4;
        const unsigned scb = cb ^ ((row & 7) << 4);
        llds16(Kp + (size_t)(kv + row) * 64 + (scb >> 1), &sK[bi][0] + t*8);
        llds16(Vp + (size_t)row * S_LEN + kv + (scb >> 1), &sV[bi][0] + t*8);
    };

    stageKV(0, 0);
    stageKV(1, 1);
    int cur = 0, st2 = 2;

    for (int tt = 0; tt < ntB; ++tt) {
        if (tt < ntB - 1) CBAR(2); else CBAR(0);
        if (tt + 2 < ntB) stageKV(tt + 2, st2);
        if (tt <= tmax_w) {
            const int kv0 = tt * 64;
            const float nm = -m_run;
            f32x16 s0, s1;
            #pragma unroll
            for (int r = 0; r < 16; ++r) { s0[r] = nm; s1[r] = nm; }
            __builtin_amdgcn_s_setprio(1);
            #pragma unroll
            for (int kd = 0; kd < 4; ++kd) {
                const unsigned bc = ((unsigned)(32*kd + 16*hi)) ^ ((lq & 7) << 4);
                bf16x8 k0 = *(const bf16x8*)((const char*)&sK[cur][0] + lq*128 + bc);
                bf16x8 k1 = *(const bf16x8*)((const char*)&sK[cur][0] + (32 + lq)*128 + bc);
                s0 = __builtin_amdgcn_mfma_f32_32x32x16_bf16(k0, qf[kd], s0, 0, 0, 0);
                s1 = __builtin_amdgcn_mfma_f32_32x32x16_bf16(k1, qf[kd], s1, 0, 0, 0);
            }
            __builtin_amdgcn_s_setprio(0);
            if (kv0 + 63 > q0w) {
                #pragma unroll
                for (int r = 0; r < 16; ++r) {
                    const int kvg = kv0 + (r & 3) + 8*(r >> 2) + 4*hi;
                    if (kvg > qg)      s0[r] = -INFINITY;
                    if (kvg + 32 > qg) s1[r] = -INFINITY;
                }
            }
            float mx[8];
            #pragma unroll
            for (int r = 0; r < 8; ++r)
                mx[r] = fmaxf(fmaxf(s0[r], s0[r+8]), fmaxf(s1[r], s1[r+8]));
            float tm = fmaxf(fmaxf(fmaxf(mx[0], mx[1]), fmaxf(mx[2], mx[3])),
                             fmaxf(fmaxf(mx[4], mx[5]), fmaxf(mx[6], mx[7])));
            tm = fmaxf(tm, __shfl_xor(tm, 32));
            if (!__all(tm <= 8.0f)) {
                const float dd = fmaxf(tm, 0.f);
                const float al = __builtin_amdgcn_exp2f(-dd);
                m_run += dd;
                l_run *= al;
                #pragma unroll
                for (int r = 0; r < 16; ++r) { accO0[r] *= al; accO1[r] *= al; }
                #pragma unroll
                for (int r = 0; r < 16; ++r) { s0[r] -= dd; s1[r] -= dd; }
            }
            #pragma unroll
            for (int r = 0; r < 16; ++r) {
                s0[r] = __builtin_amdgcn_exp2f(s0[r]);
                s1[r] = __builtin_amdgcn_exp2f(s1[r]);
            }
            float sm[8];
            #pragma unroll
            for (int r = 0; r < 8; ++r)
                sm[r] = (s0[r] + s0[r+8]) + (s1[r] + s1[r+8]);
            float rs = ((sm[0]+sm[1]) + (sm[2]+sm[3])) + ((sm[4]+sm[5]) + (sm[6]+sm[7]));
            rs += __shfl_xor(rs, 32);
            l_run += rs;

            #pragma unroll
            for (int ks = 0; ks < 4; ++ks) {
                const f32x16& e = (ks & 2) ? s1 : s0;
                const int rb = (ks & 1) * 8;
                unsigned x0 = cvtpk(e[rb + 0], e[rb + 1]);
                unsigned x1 = cvtpk(e[rb + 2], e[rb + 3]);
                unsigned y0 = cvtpk(e[rb + 4], e[rb + 5]);
                unsigned y1 = cvtpk(e[rb + 6], e[rb + 7]);
                plswap(x0, y0);
                plswap(x1, y1);
                union { unsigned u[4]; bf16x8 v; } pb;
                pb.u[0] = x0; pb.u[1] = x1; pb.u[2] = y0; pb.u[3] = y1;
                const unsigned bc = ((unsigned)(32*ks + 16*hi)) ^ ((lq & 7) << 4);
                bf16x8 v0 = *(const bf16x8*)((const char*)&sV[cur][0] + lq*128 + bc);
                bf16x8 v1 = *(const bf16x8*)((const char*)&sV[cur][0] + (32 + lq)*128 + bc);
                __builtin_amdgcn_s_setprio(1);
                accO0 = __builtin_amdgcn_mfma_f32_32x32x16_bf16(v0, pb.v, accO0, 0, 0, 0);
                accO1 = __builtin_amdgcn_mfma_f32_32x32x16_bf16(v1, pb.v, accO1, 0, 0, 0);
                __builtin_amdgcn_s_setprio(0);
            }
        }
        cur = (cur == 2) ? 0 : cur + 1;
        st2 = (st2 == 2) ? 0 : st2 + 1;
    }

    const float inv = 1.0f / l_run;
    u16* orow = O + (((size_t)(b * S_LEN) + q0w + lq)) * (NH*HD) + h*64;
    #pragma unroll
    for (int g = 0; g < 4; ++g) {
        uint2 w0, w1;
        w0.x = cvtpk(accO0[4*g + 0] * inv, accO0[4*g + 1] * inv);
        w0.y = cvtpk(accO0[4*g + 2] * inv, accO0[4*g + 3] * inv);
        *(uint2*)(orow + 8*g + 4*hi) = w0;
        w1.x = cvtpk(accO1[4*g + 0] * inv, accO1[4*g + 1] * inv);
        w1.y = cvtpk(accO1[4*g + 2] * inv, accO1[4*g + 3] * inv);
        *(uint2*)(orow + 32 + 8*g + 4*hi) = w1;
    }
}

// ---------------- host launcher ----------------
extern "C" void kernel_launch(void* const* d_in, const int* in_sizes, int n_in,
                              void* d_out, int out_size, void* d_ws, size_t ws_size,
                              hipStream_t stream) {
    const float* x  = (const float*)d_in[0];
    const float* Wq = (const float*)d_in[1];
    const float* bq = (const float*)d_in[2];
    const float* Wk = (const float*)d_in[3];
    const float* bk = (const float*)d_in[4];
    const float* Wv = (const float*)d_in[5];
    const float* bv = (const float*)d_in[6];
    const float* Wo = (const float*)d_in[7];
    const float* bo = (const float*)d_in[8];
    const float* kw = (const float*)d_in[9];

    uint8_t* ws = (uint8_t*)d_ws;
    u16*   xb    = (u16*)(ws);                    // 16 MiB
    u16*   wqkvb = (u16*)(ws + 16777216);         // 12 MiB
    u16*   wob   = (u16*)(ws + 29360128);         //  8 MiB
    u16*   qpk   = (u16*)(ws + 37748736);         // 16 MiB  [B*NH][S][64]
    u16*   kpk   = (u16*)(ws + 54525952);         //  4 MiB  [B*NKV][S][64]
    u16*   vlin  = (u16*)(ws + 58720256);         //  4 MiB  [4096][512]
    u16*   vtb   = (u16*)(ws + 62914560);         //  4 MiB  [B*NKV][64][S]
    u16*   ob    = (u16*)(ws + 67108864);         // 16 MiB  [B*S][2048]
    float* bqkv  = (float*)(ws + 83886080);       // 12 KiB
    float* rtab  = (float*)(ws + 83898368);       // 512 KiB

    // 1. fused prep
    prep_all<<<9484, 256, 0, stream>>>(x, Wq, Wk, Wv, Wo, bq, bk, bv,
                                       xb, wqkvb, wob, rtab, bqkv);

    // 2. QKV projection + fused RoPE/scale/pack epilogue (768 blocks, barrier-free)
    gemm_qkv<<<768, 256, 0, stream>>>(xb, wqkvb, bqkv, rtab, kw, qpk, kpk, vlin);

    // 3. transpose-pack V
    pack_vt<<<dim3(32, 16), 256, 0, stream>>>(vlin, vtb);

    // 4. causal flash attention
    attn_fwd<<<dim3(512), dim3(512), 0, stream>>>(qpk, kpk, vtb, ob);

    // 5. output projection (512 blocks, barrier-free)
    gemm_bt<<<512, 256, 0, stream>>>(ob, wob, bo, (float*)d_out, NROWS, HID, HID);

    (void)in_sizes; (void)n_in; (void)out_size; (void)ws_size;
}

// Round 15
// 184.517 us; speedup vs baseline: 1.2498x; 1.2498x over previous
//
#include <hip/hip_runtime.h>
#include <stdint.h>

#define S_LEN 2048
#define HID   2048
#define NH    32
#define NKV   8
#define HD    64
#define BATCH 2
#define NROWS (BATCH * S_LEN)      // 4096
#define QKVN  (NH*HD + 2*NKV*HD)   // 3072

typedef unsigned short u16;
typedef __bf16 bf16_t;
typedef bf16_t bf16x8 __attribute__((ext_vector_type(8)));
typedef float  f32x4  __attribute__((ext_vector_type(4)));
typedef float  f32x16 __attribute__((ext_vector_type(16)));
typedef u16    u16x8  __attribute__((ext_vector_type(8)));

#define LOG2E 1.4426950408889634f

__device__ __forceinline__ u16 f2bf(float f) {
    union { float f; uint32_t u; } v; v.f = f;
    uint32_t u = v.u;
    return (u16)((u + 0x7fffu + ((u >> 16) & 1u)) >> 16);
}

__device__ __forceinline__ unsigned cvtpk(float a, float b) {
    unsigned r;
    asm("v_cvt_pk_bf16_f32 %0, %1, %2" : "=v"(r) : "v"(a), "v"(b));
    return r;
}

// v_permlane32_swap_b32 a, b:  a'[l>=32] = b[l-32];  b'[l<32] = a[l+32]  (HW-verified R5)
__device__ __forceinline__ void plswap(unsigned &a, unsigned &b) {
    asm volatile("v_permlane32_swap_b32 %0, %1" : "+v"(a), "+v"(b));
}

__device__ __forceinline__ void llds16(const void* g, void* l) {
    __builtin_amdgcn_global_load_lds(
        (const __attribute__((address_space(1))) void*)g,
        (__attribute__((address_space(3))) void*)l,
        16, 0, 0);
}

// 64B-row chunk swizzle: uniform 8-slot spread (R11-verified: 0 bank conflicts).
__device__ __forceinline__ unsigned swz(unsigned row) {
    return ((row ^ (row >> 2)) & 3u) << 4;
}

#define LGKM0() do { asm volatile("s_waitcnt lgkmcnt(0)" ::: "memory"); \
                     __builtin_amdgcn_sched_barrier(0); } while (0)
#define BAR()   __builtin_amdgcn_s_barrier()

// counted-vmcnt barrier: wait for all but N newest VMEM ops, then raw barrier.
#define CBAR(N) do { \
    asm volatile("s_waitcnt vmcnt(" #N ")" ::: "memory"); \
    __builtin_amdgcn_s_barrier(); \
    __builtin_amdgcn_sched_barrier(0); \
} while (0)

// ---------------- fused prep: f32->bf16 convert (5 tensors) + RoPE table + bias concat ----------------
#define CVT_GROUPS 2359296            // 8-elem groups across x|Wq|Wk|Wv|Wo
__global__ void prep_all(const float* __restrict__ x, const float* __restrict__ wq,
                         const float* __restrict__ wk, const float* __restrict__ wv,
                         const float* __restrict__ wo,
                         const float* __restrict__ bq, const float* __restrict__ bk,
                         const float* __restrict__ bv,
                         u16* __restrict__ xb, u16* __restrict__ wqkvb, u16* __restrict__ wob,
                         float* __restrict__ rtab, float* __restrict__ bqkv) {
    int e = blockIdx.x * 256 + threadIdx.x;
    if (e < CVT_GROUPS) {
        const float* s; u16* d; int o;
        if (e < 1048576)      { s = x;  d = xb;                 o = e; }
        else if (e < 1572864) { s = wq; d = wqkvb;              o = e - 1048576; }
        else if (e < 1703936) { s = wk; d = wqkvb + 2048*2048;  o = e - 1572864; }
        else if (e < 1835008) { s = wv; d = wqkvb + 2560*2048;  o = e - 1703936; }
        else                  { s = wo; d = wob;                o = e - 1835008; }
        const float4* sp = (const float4*)s;
        float4 a = sp[2*(size_t)o], b = sp[2*(size_t)o + 1];
        u16x8 r;
        r[0]=f2bf(a.x); r[1]=f2bf(a.y); r[2]=f2bf(a.z); r[3]=f2bf(a.w);
        r[4]=f2bf(b.x); r[5]=f2bf(b.y); r[6]=f2bf(b.z); r[7]=f2bf(b.w);
        *(u16x8*)(d + 8*(size_t)o) = r;
    } else if (e < CVT_GROUPS + 65536) {
        int idx = e - CVT_GROUPS;          // s*32 + i
        int i = idx & 31, s = idx >> 5;
        float invf = exp2f(-(float)i * (13.287712379549449f / 32.0f));
        float ang = (float)s * invf;
        float sn, cs;
        sincosf(ang, &sn, &cs);
        rtab[idx] = cs;
        rtab[S_LEN*32 + idx] = sn;
    } else if (e < CVT_GROUPS + 65536 + QKVN) {
        int i = e - CVT_GROUPS - 65536;
        bqkv[i] = (i < 2048) ? bq[i] : (i < 2560 ? bk[i - 2048] : bv[i - 2560]);
    }
}

// =====================================================================================
// GEMM geometry (R8 structure, best measured): block 128x256, 4 waves (2M x 2N),
// wave tile 64x128, BK=32, 16x16x32 MFMA, 3-buffer counted pipeline, phase-split
// K-step (barrier/lgkm0/setprio/16 MFMA x2), uniform swizzle swz(row),
// bm-major XCD chunking.
// =====================================================================================

// ---------------- QKV GEMM + fused RoPE/scale/pack epilogue ----------------
__global__ __launch_bounds__(256, 2) void gemm_qkv(
    const u16* __restrict__ A, const u16* __restrict__ Bw,
    const float* __restrict__ bias, const float* __restrict__ rtab,
    const float* __restrict__ kw,
    u16* __restrict__ qpk, u16* __restrict__ kpk, u16* __restrict__ vlin)
{
    const int M = NROWS, N = QKVN, K = HID;
    const int nbn = N >> 8;                 // 12
    const int nwg = (M >> 7) * nbn;         // 384
    int wg = blockIdx.x;
    wg = (wg & 7) * (nwg >> 3) + (wg >> 3); // XCD -> contiguous chunk
    const int bm = wg / nbn, bn = wg % nbn; // bm-major: XCD A-panel L2-resident
    const int brow = bm << 7, bcol = bn << 8;

    __shared__ u16 sbuf[3][12288];          // A 8KB + B 16KB per buf

    const int t = threadIdx.x;
    const int lane = t & 63, wid = t >> 6;
    const int wr = wid >> 1, wn = wid & 1;
    const int lr = lane & 15, lhi = lane >> 4;

    auto stageA = [&](int kt, int bi) {     // A(2) + B0 (1)
        const int k0 = kt << 5;
        #pragma unroll
        for (int i = 0; i < 2; ++i) {
            const unsigned off = ((unsigned)t << 4) + ((unsigned)i << 12);
            const unsigned row = off >> 6;
            const unsigned scb = (off & 63) ^ swz(row);
            llds16(A + (size_t)(brow + row) * K + (k0 + (scb >> 1)), &sbuf[bi][0] + (off >> 1));
        }
        {
            const unsigned off = ((unsigned)t << 4);
            const unsigned row = off >> 6;
            const unsigned scb = (off & 63) ^ swz(row);
            llds16(Bw + (size_t)(bcol + row) * K + (k0 + (scb >> 1)), &sbuf[bi][4096] + (off >> 1));
        }
    };
    auto stageB = [&](int kt, int bi) {     // B1..B3 (3)
        const int k0 = kt << 5;
        #pragma unroll
        for (int i = 1; i < 4; ++i) {
            const unsigned off = ((unsigned)t << 4) + ((unsigned)i << 12);
            const unsigned row = off >> 6;
            const unsigned scb = (off & 63) ^ swz(row);
            llds16(Bw + (size_t)(bcol + row) * K + (k0 + (scb >> 1)), &sbuf[bi][4096] + (off >> 1));
        }
    };

    f32x4 acc[4][8] = {};
    const int nk = K >> 5;                  // 64

    stageA(0, 0); stageB(0, 0);
    stageA(1, 1); stageB(1, 1);
    asm volatile("s_waitcnt vmcnt(6)" ::: "memory");  // tile 0 resident
    BAR();

    int cur = 0, st2 = 2;
    for (int kt = 0; kt < nk; ++kt) {
        const char* sA = (const char*)&sbuf[cur][0];
        const char* sB = (const char*)&sbuf[cur][4096];
        bf16x8 af[4], bfv[8];
        // ---- phase A: reads + stage-issue, barrier, MFMA n=0..3 ----
        #pragma unroll
        for (int m = 0; m < 4; ++m) {
            const unsigned row = wr*64 + m*16 + lr;
            af[m] = *(const bf16x8*)(sA + row*64 + ((unsigned)(lhi*16) ^ swz(row)));
        }
        #pragma unroll
        for (int n = 0; n < 4; ++n) {
            const unsigned row = wn*128 + n*16 + lr;
            bfv[n] = *(const bf16x8*)(sB + row*64 + ((unsigned)(lhi*16) ^ swz(row)));
        }
        if (kt + 2 < nk) stageA(kt + 2, st2);
        BAR();
        LGKM0();
        __builtin_amdgcn_s_setprio(1);
        #pragma unroll
        for (int m = 0; m < 4; ++m)
            #pragma unroll
            for (int n = 0; n < 4; ++n)
                acc[m][n] = __builtin_amdgcn_mfma_f32_16x16x32_bf16(af[m], bfv[n], acc[m][n], 0, 0, 0);
        __builtin_amdgcn_s_setprio(0);
        BAR();
        // ---- phase B: reads + stage-issue, barrier, MFMA n=4..7 ----
        #pragma unroll
        for (int n = 4; n < 8; ++n) {
            const unsigned row = wn*128 + n*16 + lr;
            bfv[n] = *(const bf16x8*)(sB + row*64 + ((unsigned)(lhi*16) ^ swz(row)));
        }
        if (kt + 2 < nk) stageB(kt + 2, st2);
        BAR();
        LGKM0();
        __builtin_amdgcn_s_setprio(1);
        #pragma unroll
        for (int m = 0; m < 4; ++m)
            #pragma unroll
            for (int n = 4; n < 8; ++n)
                acc[m][n] = __builtin_amdgcn_mfma_f32_16x16x32_bf16(af[m], bfv[n], acc[m][n], 0, 0, 0);
        __builtin_amdgcn_s_setprio(0);
        // ---- closing: ensure next tile resident, then barrier ----
        if (kt + 2 < nk) {
            asm volatile("s_waitcnt vmcnt(6)" ::: "memory");
            BAR();
        } else if (kt + 1 < nk) {
            asm volatile("s_waitcnt vmcnt(0)" ::: "memory");
            BAR();
        }
        cur = (cur == 2) ? 0 : cur + 1;
        st2 = (st2 == 2) ? 0 : st2 + 1;
    }

    const int rowb = brow + wr*64;
    #pragma unroll
    for (int hg = 0; hg < 2; ++hg) {        // two 64-col head blocks per wave
        const int c64 = bcol + wn*128 + hg*64;
        const int hb  = c64 >> 6;           // 0..47: <32 Q, <40 K, else V
        if (hb < 40) {
            const bool isQ = hb < 32;
            const float sc = isQ ? (0.125f * LOG2E * kw[hb]) : 1.0f;
            u16* dst = isQ ? qpk : kpk;
            const int nheads = isQ ? 32 : 8;
            const int hloc = isQ ? hb : (hb - 32);
            #pragma unroll
            for (int m = 0; m < 4; ++m) {
                #pragma unroll
                for (int nn = 0; nn < 2; ++nn) {
                    const int n = 4*hg + nn;
                    const int i = nn*16 + lr;
                    const float b1 = bias[c64 + i];
                    const float b2 = bias[c64 + i + 32];
                    #pragma unroll
                    for (int j = 0; j < 4; ++j) {
                        const int row = rowb + m*16 + lhi*4 + j;
                        const int s = row & (S_LEN - 1);
                        const int bb = row >> 11;
                        const float x1 = acc[m][n][j] + b1;
                        const float x2 = acc[m][n+2][j] + b2;
                        const float cs = rtab[s*32 + i];
                        const float sn = rtab[S_LEN*32 + s*32 + i];
                        const size_t base = ((size_t)(bb*nheads + hloc)) * (S_LEN*64) + (size_t)s*64;
                        dst[base + i]      = f2bf((x1*cs - x2*sn) * sc);
                        dst[base + i + 32] = f2bf((x2*cs + x1*sn) * sc);
                    }
                }
            }
        } else {
            #pragma unroll
            for (int m = 0; m < 4; ++m) {
                #pragma unroll
                for (int nn = 0; nn < 4; ++nn) {
                    const int col = c64 + nn*16 + lr;
                    const float bv = bias[col];
                    #pragma unroll
                    for (int j = 0; j < 4; ++j) {
                        const int row = rowb + m*16 + lhi*4 + j;
                        vlin[(size_t)row * 512 + (col - 2560)] = f2bf(acc[m][nn + 4*hg][j] + bv);
                    }
                }
            }
        }
    }
}

// ---------------- o-proj GEMM, C[M][N] = A @ Bw^T + bias (f32 out) ----------------
__global__ __launch_bounds__(256, 2) void gemm_bt(
    const u16* __restrict__ A, const u16* __restrict__ Bw,
    const float* __restrict__ bias, float* __restrict__ C,
    int M, int N, int K)
{
    const int nbn = N >> 8;
    const int nwg = (M >> 7) * nbn;
    int wg = blockIdx.x;
    wg = (wg & 7) * (nwg >> 3) + (wg >> 3);
    const int bm = wg / nbn, bn = wg % nbn;
    const int brow = bm << 7, bcol = bn << 8;

    __shared__ u16 sbuf[3][12288];

    const int t = threadIdx.x;
    const int lane = t & 63, wid = t >> 6;
    const int wr = wid >> 1, wn = wid & 1;
    const int lr = lane & 15, lhi = lane >> 4;

    auto stageA = [&](int kt, int bi) {
        const int k0 = kt << 5;
        #pragma unroll
        for (int i = 0; i < 2; ++i) {
            const unsigned off = ((unsigned)t << 4) + ((unsigned)i << 12);
            const unsigned row = off >> 6;
            const unsigned scb = (off & 63) ^ swz(row);
            llds16(A + (size_t)(brow + row) * K + (k0 + (scb >> 1)), &sbuf[bi][0] + (off >> 1));
        }
        {
            const unsigned off = ((unsigned)t << 4);
            const unsigned row = off >> 6;
            const unsigned scb = (off & 63) ^ swz(row);
            llds16(Bw + (size_t)(bcol + row) * K + (k0 + (scb >> 1)), &sbuf[bi][4096] + (off >> 1));
        }
    };
    auto stageB = [&](int kt, int bi) {
        const int k0 = kt << 5;
        #pragma unroll
        for (int i = 1; i < 4; ++i) {
            const unsigned off = ((unsigned)t << 4) + ((unsigned)i << 12);
            const unsigned row = off >> 6;
            const unsigned scb = (off & 63) ^ swz(row);
            llds16(Bw + (size_t)(bcol + row) * K + (k0 + (scb >> 1)), &sbuf[bi][4096] + (off >> 1));
        }
    };

    f32x4 acc[4][8] = {};
    const int nk = K >> 5;

    stageA(0, 0); stageB(0, 0);
    stageA(1, 1); stageB(1, 1);
    asm volatile("s_waitcnt vmcnt(6)" ::: "memory");
    BAR();

    int cur = 0, st2 = 2;
    for (int kt = 0; kt < nk; ++kt) {
        const char* sA = (const char*)&sbuf[cur][0];
        const char* sB = (const char*)&sbuf[cur][4096];
        bf16x8 af[4], bfv[8];
        #pragma unroll
        for (int m = 0; m < 4; ++m) {
            const unsigned row = wr*64 + m*16 + lr;
            af[m] = *(const bf16x8*)(sA + row*64 + ((unsigned)(lhi*16) ^ swz(row)));
        }
        #pragma unroll
        for (int n = 0; n < 4; ++n) {
            const unsigned row = wn*128 + n*16 + lr;
            bfv[n] = *(const bf16x8*)(sB + row*64 + ((unsigned)(lhi*16) ^ swz(row)));
        }
        if (kt + 2 < nk) stageA(kt + 2, st2);
        BAR();
        LGKM0();
        __builtin_amdgcn_s_setprio(1);
        #pragma unroll
        for (int m = 0; m < 4; ++m)
            #pragma unroll
            for (int n = 0; n < 4; ++n)
                acc[m][n] = __builtin_amdgcn_mfma_f32_16x16x32_bf16(af[m], bfv[n], acc[m][n], 0, 0, 0);
        __builtin_amdgcn_s_setprio(0);
        BAR();
        #pragma unroll
        for (int n = 4; n < 8; ++n) {
            const unsigned row = wn*128 + n*16 + lr;
            bfv[n] = *(const bf16x8*)(sB + row*64 + ((unsigned)(lhi*16) ^ swz(row)));
        }
        if (kt + 2 < nk) stageB(kt + 2, st2);
        BAR();
        LGKM0();
        __builtin_amdgcn_s_setprio(1);
        #pragma unroll
        for (int m = 0; m < 4; ++m)
            #pragma unroll
            for (int n = 4; n < 8; ++n)
                acc[m][n] = __builtin_amdgcn_mfma_f32_16x16x32_bf16(af[m], bfv[n], acc[m][n], 0, 0, 0);
        __builtin_amdgcn_s_setprio(0);
        if (kt + 2 < nk) {
            asm volatile("s_waitcnt vmcnt(6)" ::: "memory");
            BAR();
        } else if (kt + 1 < nk) {
            asm volatile("s_waitcnt vmcnt(0)" ::: "memory");
            BAR();
        }
        cur = (cur == 2) ? 0 : cur + 1;
        st2 = (st2 == 2) ? 0 : st2 + 1;
    }

    #pragma unroll
    for (int m = 0; m < 4; ++m) {
        #pragma unroll
        for (int n = 0; n < 8; ++n) {
            const int col = bcol + wn*128 + n*16 + lr;
            const float bv = bias[col];
            #pragma unroll
            for (int j = 0; j < 4; ++j) {
                const int row = brow + wr*64 + m*16 + lhi*4 + j;
                C[(size_t)row * N + col] = acc[m][n][j] + bv;
            }
        }
    }
}

// ---------------- pack V transposed: bf16 vlin[row][512] -> vtb[b*8+kvh][64][S] ----------------
__global__ void pack_vt(const u16* __restrict__ vlin, u16* __restrict__ vtb) {
    __shared__ u16 tile[64][67];
    const int st = blockIdx.x;          // s-tile
    const int bk = blockIdx.y;          // b*8 + kvh
    const int t = threadIdx.x;
    const int b = bk >> 3, kvh = bk & 7;
    const int r = t >> 2, cg = (t & 3) << 4;
    const u16* src = vlin + ((size_t)(b*S_LEN + st*64 + r)) * 512 + kvh*64 + cg;
    #pragma unroll
    for (int j = 0; j < 16; ++j) tile[r][cg + j] = src[j];
    __syncthreads();
    const int d = t >> 2, sg = (t & 3) << 4;
    u16* dst = vtb + ((size_t)(bk*64 + d)) * S_LEN + st*64 + sg;
    #pragma unroll
    for (int j = 0; j < 16; ++j) dst[j] = tile[sg + j][d];
}

// ---------------- flash attention: 8 waves x 32 q-rows, swapped 32x32 MFMA ----------------
__global__ __launch_bounds__(512, 4) void attn_fwd(
    const u16* __restrict__ Q,      // [B*NH][S][64] packed, scaled
    const u16* __restrict__ Kk,     // [B*NKV][S][64]
    const u16* __restrict__ Vt,     // [B*NKV][64][S]
    u16* __restrict__ O)            // [B*S][NH*64]
{
    __shared__ u16 sK[3][64 * 64];
    __shared__ u16 sV[3][64 * 64];

    const int t = threadIdx.x;
    const int lane = t & 63, wid = t >> 6;
    const int hi = lane >> 5, lq = lane & 31;
    const int bid = blockIdx.x;
    const int qb = (bid < 256) ? (7 - (bid >> 6)) : ((bid >> 6) - 4);
    const int bh = bid & 63;
    const int b = bh >> 5, h = bh & 31;
    const int kvh = h >> 2;

    const u16* Kp = Kk + ((size_t)(b*NKV + kvh)) * (S_LEN * 64);
    const u16* Vp = Vt + ((size_t)(b*NKV + kvh)) * (64 * S_LEN);

    const int q0w = qb*256 + wid*32;
    const int qg  = q0w + lq;

    const u16* Qrow = Q + (((size_t)bh) * S_LEN + qg) * 64 + 8*hi;
    bf16x8 qf[4];
    #pragma unroll
    for (int kd = 0; kd < 4; ++kd)
        qf[kd] = *(const bf16x8*)(Qrow + 16*kd);

    f32x16 accO0 = {}, accO1 = {};
    float m_run = 0.f, l_run = 0.f;

    const int ntB = 4*qb + 4;
    const int tmax_w = (q0w + 31) >> 6;

    auto stageKV = [&](int kt, int bi) {
        const int kv = kt << 6;
        const unsigned row = t >> 3, cb = (t & 7) << 4;
        const unsigned scb = cb ^ ((row & 7) << 4);
        llds16(Kp + (size_t)(kv + row) * 64 + (scb >> 1), &sK[bi][0] + t*8);
        llds16(Vp + (size_t)row * S_LEN + kv + (scb >> 1), &sV[bi][0] + t*8);
    };

    stageKV(0, 0);
    stageKV(1, 1);
    int cur = 0, st2 = 2;

    for (int tt = 0; tt < ntB; ++tt) {
        if (tt < ntB - 1) CBAR(2); else CBAR(0);
        if (tt + 2 < ntB) stageKV(tt + 2, st2);
        if (tt <= tmax_w) {
            const int kv0 = tt * 64;
            const float nm = -m_run;
            f32x16 s0, s1;
            #pragma unroll
            for (int r = 0; r < 16; ++r) { s0[r] = nm; s1[r] = nm; }
            __builtin_amdgcn_s_setprio(1);
            #pragma unroll
            for (int kd = 0; kd < 4; ++kd) {
                const unsigned bc = ((unsigned)(32*kd + 16*hi)) ^ ((lq & 7) << 4);
                bf16x8 k0 = *(const bf16x8*)((const char*)&sK[cur][0] + lq*128 + bc);
                bf16x8 k1 = *(const bf16x8*)((const char*)&sK[cur][0] + (32 + lq)*128 + bc);
                s0 = __builtin_amdgcn_mfma_f32_32x32x16_bf16(k0, qf[kd], s0, 0, 0, 0);
                s1 = __builtin_amdgcn_mfma_f32_32x32x16_bf16(k1, qf[kd], s1, 0, 0, 0);
            }
            __builtin_amdgcn_s_setprio(0);
            if (kv0 + 63 > q0w) {
                #pragma unroll
                for (int r = 0; r < 16; ++r) {
                    const int kvg = kv0 + (r & 3) + 8*(r >> 2) + 4*hi;
                    if (kvg > qg)      s0[r] = -INFINITY;
                    if (kvg + 32 > qg) s1[r] = -INFINITY;
                }
            }
            float mx[8];
            #pragma unroll
            for (int r = 0; r < 8; ++r)
                mx[r] = fmaxf(fmaxf(s0[r], s0[r+8]), fmaxf(s1[r], s1[r+8]));
            float tm = fmaxf(fmaxf(fmaxf(mx[0], mx[1]), fmaxf(mx[2], mx[3])),
                             fmaxf(fmaxf(mx[4], mx[5]), fmaxf(mx[6], mx[7])));
            tm = fmaxf(tm, __shfl_xor(tm, 32));
            if (!__all(tm <= 8.0f)) {
                const float dd = fmaxf(tm, 0.f);
                const float al = __builtin_amdgcn_exp2f(-dd);
                m_run += dd;
                l_run *= al;
                #pragma unroll
                for (int r = 0; r < 16; ++r) { accO0[r] *= al; accO1[r] *= al; }
                #pragma unroll
                for (int r = 0; r < 16; ++r) { s0[r] -= dd; s1[r] -= dd; }
            }
            #pragma unroll
            for (int r = 0; r < 16; ++r) {
                s0[r] = __builtin_amdgcn_exp2f(s0[r]);
                s1[r] = __builtin_amdgcn_exp2f(s1[r]);
            }
            float sm[8];
            #pragma unroll
            for (int r = 0; r < 8; ++r)
                sm[r] = (s0[r] + s0[r+8]) + (s1[r] + s1[r+8]);
            float rs = ((sm[0]+sm[1]) + (sm[2]+sm[3])) + ((sm[4]+sm[5]) + (sm[6]+sm[7]));
            rs += __shfl_xor(rs, 32);
            l_run += rs;

            #pragma unroll
            for (int ks = 0; ks < 4; ++ks) {
                const f32x16& e = (ks & 2) ? s1 : s0;
                const int rb = (ks & 1) * 8;
                unsigned x0 = cvtpk(e[rb + 0], e[rb + 1]);
                unsigned x1 = cvtpk(e[rb + 2], e[rb + 3]);
                unsigned y0 = cvtpk(e[rb + 4], e[rb + 5]);
                unsigned y1 = cvtpk(e[rb + 6], e[rb + 7]);
                plswap(x0, y0);
                plswap(x1, y1);
                union { unsigned u[4]; bf16x8 v; } pb;
                pb.u[0] = x0; pb.u[1] = x1; pb.u[2] = y0; pb.u[3] = y1;
                const unsigned bc = ((unsigned)(32*ks + 16*hi)) ^ ((lq & 7) << 4);
                bf16x8 v0 = *(const bf16x8*)((const char*)&sV[cur][0] + lq*128 + bc);
                bf16x8 v1 = *(const bf16x8*)((const char*)&sV[cur][0] + (32 + lq)*128 + bc);
                __builtin_amdgcn_s_setprio(1);
                accO0 = __builtin_amdgcn_mfma_f32_32x32x16_bf16(v0, pb.v, accO0, 0, 0, 0);
                accO1 = __builtin_amdgcn_mfma_f32_32x32x16_bf16(v1, pb.v, accO1, 0, 0, 0);
                __builtin_amdgcn_s_setprio(0);
            }
        }
        cur = (cur == 2) ? 0 : cur + 1;
        st2 = (st2 == 2) ? 0 : st2 + 1;
    }

    const float inv = 1.0f / l_run;
    u16* orow = O + (((size_t)(b * S_LEN) + q0w + lq)) * (NH*HD) + h*64;
    #pragma unroll
    for (int g = 0; g < 4; ++g) {
        uint2 w0, w1;
        w0.x = cvtpk(accO0[4*g + 0] * inv, accO0[4*g + 1] * inv);
        w0.y = cvtpk(accO0[4*g + 2] * inv, accO0[4*g + 3] * inv);
        *(uint2*)(orow + 8*g + 4*hi) = w0;
        w1.x = cvtpk(accO1[4*g + 0] * inv, accO1[4*g + 1] * inv);
        w1.y = cvtpk(accO1[4*g + 2] * inv, accO1[4*g + 3] * inv);
        *(uint2*)(orow + 32 + 8*g + 4*hi) = w1;
    }
}

// ---------------- host launcher ----------------
extern "C" void kernel_launch(void* const* d_in, const int* in_sizes, int n_in,
                              void* d_out, int out_size, void* d_ws, size_t ws_size,
                              hipStream_t stream) {
    const float* x  = (const float*)d_in[0];
    const float* Wq = (const float*)d_in[1];
    const float* bq = (const float*)d_in[2];
    const float* Wk = (const float*)d_in[3];
    const float* bk = (const float*)d_in[4];
    const float* Wv = (const float*)d_in[5];
    const float* bv = (const float*)d_in[6];
    const float* Wo = (const float*)d_in[7];
    const float* bo = (const float*)d_in[8];
    const float* kw = (const float*)d_in[9];

    uint8_t* ws = (uint8_t*)d_ws;
    u16*   xb    = (u16*)(ws);                    // 16 MiB
    u16*   wqkvb = (u16*)(ws + 16777216);         // 12 MiB
    u16*   wob   = (u16*)(ws + 29360128);         //  8 MiB
    u16*   qpk   = (u16*)(ws + 37748736);         // 16 MiB  [B*NH][S][64]
    u16*   kpk   = (u16*)(ws + 54525952);         //  4 MiB  [B*NKV][S][64]
    u16*   vlin  = (u16*)(ws + 58720256);         //  4 MiB  [4096][512]
    u16*   vtb   = (u16*)(ws + 62914560);         //  4 MiB  [B*NKV][64][S]
    u16*   ob    = (u16*)(ws + 67108864);         // 16 MiB  [B*S][2048]
    float* bqkv  = (float*)(ws + 83886080);       // 12 KiB
    float* rtab  = (float*)(ws + 83898368);       // 512 KiB

    // 1. fused prep
    prep_all<<<9484, 256, 0, stream>>>(x, Wq, Wk, Wv, Wo, bq, bk, bv,
                                       xb, wqkvb, wob, rtab, bqkv);

    // 2. QKV projection + fused RoPE/scale/pack epilogue
    gemm_qkv<<<384, 256, 0, stream>>>(xb, wqkvb, bqkv, rtab, kw, qpk, kpk, vlin);

    // 3. transpose-pack V
    pack_vt<<<dim3(32, 16), 256, 0, stream>>>(vlin, vtb);

    // 4. causal flash attention
    attn_fwd<<<dim3(512), dim3(512), 0, stream>>>(qpk, kpk, vtb, ob);

    // 5. output projection
    gemm_bt<<<256, 256, 0, stream>>>(ob, wob, bo, (float*)d_out, NROWS, HID, HID);

    (void)in_sizes; (void)n_in; (void)out_size; (void)ws_size;
}

// Round 16
// 183.499 us; speedup vs baseline: 1.2568x; 1.0055x over previous
//
#include <hip/hip_runtime.h>
#include <stdint.h>

#define S_LEN 2048
#define HID   2048
#define NH    32
#define NKV   8
#define HD    64
#define BATCH 2
#define NROWS (BATCH * S_LEN)      // 4096
#define QKVN  (NH*HD + 2*NKV*HD)   // 3072

typedef unsigned short u16;
typedef __bf16 bf16_t;
typedef bf16_t bf16x8 __attribute__((ext_vector_type(8)));
typedef float  f32x4  __attribute__((ext_vector_type(4)));
typedef float  f32x16 __attribute__((ext_vector_type(16)));
typedef u16    u16x8  __attribute__((ext_vector_type(8)));

#define LOG2E 1.4426950408889634f

__device__ __forceinline__ u16 f2bf(float f) {
    union { float f; uint32_t u; } v; v.f = f;
    uint32_t u = v.u;
    return (u16)((u + 0x7fffu + ((u >> 16) & 1u)) >> 16);
}

__device__ __forceinline__ unsigned cvtpk(float a, float b) {
    unsigned r;
    asm("v_cvt_pk_bf16_f32 %0, %1, %2" : "=v"(r) : "v"(a), "v"(b));
    return r;
}

// v_permlane32_swap_b32 a, b:  a'[l>=32] = b[l-32];  b'[l<32] = a[l+32]  (HW-verified R5)
__device__ __forceinline__ void plswap(unsigned &a, unsigned &b) {
    asm volatile("v_permlane32_swap_b32 %0, %1" : "+v"(a), "+v"(b));
}

__device__ __forceinline__ void llds16(const void* g, void* l) {
    __builtin_amdgcn_global_load_lds(
        (const __attribute__((address_space(1))) void*)g,
        (__attribute__((address_space(3))) void*)l,
        16, 0, 0);
}

// 64B-row chunk swizzle (R15 2-phase GEMM path)
__device__ __forceinline__ unsigned swz(unsigned row) {
    return ((row ^ (row >> 2)) & 3u) << 4;
}

#define LGKM0() do { asm volatile("s_waitcnt lgkmcnt(0)" ::: "memory"); \
                     __builtin_amdgcn_sched_barrier(0); } while (0)
#define BAR()   __builtin_amdgcn_s_barrier()

#define CBAR(N) do { \
    asm volatile("s_waitcnt vmcnt(" #N ")" ::: "memory"); \
    __builtin_amdgcn_s_barrier(); \
    __builtin_amdgcn_sched_barrier(0); \
} while (0)

// ---------------- fused prep: f32->bf16 convert (5 tensors) + RoPE table + bias concat ----------------
#define CVT_GROUPS 2359296
__global__ void prep_all(const float* __restrict__ x, const float* __restrict__ wq,
                         const float* __restrict__ wk, const float* __restrict__ wv,
                         const float* __restrict__ wo,
                         const float* __restrict__ bq, const float* __restrict__ bk,
                         const float* __restrict__ bv,
                         u16* __restrict__ xb, u16* __restrict__ wqkvb, u16* __restrict__ wob,
                         float* __restrict__ rtab, float* __restrict__ bqkv) {
    int e = blockIdx.x * 256 + threadIdx.x;
    if (e < CVT_GROUPS) {
        const float* s; u16* d; int o;
        if (e < 1048576)      { s = x;  d = xb;                 o = e; }
        else if (e < 1572864) { s = wq; d = wqkvb;              o = e - 1048576; }
        else if (e < 1703936) { s = wk; d = wqkvb + 2048*2048;  o = e - 1572864; }
        else if (e < 1835008) { s = wv; d = wqkvb + 2560*2048;  o = e - 1703936; }
        else                  { s = wo; d = wob;                o = e - 1835008; }
        const float4* sp = (const float4*)s;
        float4 a = sp[2*(size_t)o], b = sp[2*(size_t)o + 1];
        u16x8 r;
        r[0]=f2bf(a.x); r[1]=f2bf(a.y); r[2]=f2bf(a.z); r[3]=f2bf(a.w);
        r[4]=f2bf(b.x); r[5]=f2bf(b.y); r[6]=f2bf(b.z); r[7]=f2bf(b.w);
        *(u16x8*)(d + 8*(size_t)o) = r;
    } else if (e < CVT_GROUPS + 65536) {
        int idx = e - CVT_GROUPS;
        int i = idx & 31, s = idx >> 5;
        float invf = exp2f(-(float)i * (13.287712379549449f / 32.0f));
        float ang = (float)s * invf;
        float sn, cs;
        sincosf(ang, &sn, &cs);
        rtab[idx] = cs;
        rtab[S_LEN*32 + idx] = sn;
    } else if (e < CVT_GROUPS + 65536 + QKVN) {
        int i = e - CVT_GROUPS - 65536;
        bqkv[i] = (i < 2048) ? bq[i] : (i < 2560 ? bk[i - 2048] : bv[i - 2560]);
    }
}

// =====================================================================================
// QKV GEMM (R16): 8-phase 256x256 schedule, BK=64, 8 waves (2Mx4N), 512 threads.
// LDS 128 KB = 2 K-tile buffers x (A 256x64 + B 256x64) bf16. Per phase:
// {ds-read quadrant subtile || stage 1 unit (2 llds16)} -> bar -> lgkm0 -> 16 MFMA -> bar.
// vmcnt(4) at phases 4 and 8. Stage map derived+window-verified (see R16 notes).
// =====================================================================================
__global__ __launch_bounds__(512, 2) void gemm_qkv(
    const u16* __restrict__ A, const u16* __restrict__ Bw,
    const float* __restrict__ bias, const float* __restrict__ rtab,
    const float* __restrict__ kw,
    u16* __restrict__ qpk, u16* __restrict__ kpk, u16* __restrict__ vlin)
{
    const int K = HID;
    const int nbn = QKVN >> 8;              // 12
    const int nwg = (NROWS >> 8) * nbn;     // 192
    int wg = blockIdx.x;
    wg = (wg & 7) * (nwg >> 3) + (wg >> 3); // XCD chunks of 24
    const int bm = wg / nbn, bn = wg % nbn;
    const int brow = bm << 8, bcol = bn << 8;

    __shared__ u16 lds[2][32768];           // per buf: A [0,16384) u16, B [16384,32768)

    const int t = threadIdx.x;
    const int lane = t & 63, wid = t >> 6;
    const int wm = wid >> 2, wn = wid & 3;  // 2 x 4 waves
    const int lr = lane & 15, lhi = lane >> 4;

    // stage A unit (mh): rows {mh*64..+63} U {128+mh*64..+63} of A tile, 2 llds16
    auto stgA = [&](int b, int mh, int kt) {
        const int k0 = kt << 6;
        #pragma unroll
        for (int i = 0; i < 2; ++i) {
            const unsigned row = (unsigned)(i*128 + mh*64) + (t >> 3);
            const unsigned cb  = (t & 7) << 4;
            const unsigned scb = cb ^ ((row & 7) << 4);
            llds16(A + (size_t)(brow + row) * K + (k0 + (scb >> 1)),
                   &lds[b][0] + (((row << 7) + cb) >> 1));
        }
    };
    // stage B unit (nh): rows {wn*64+nh*32..+31} for wn=0..3, 2 llds16
    auto stgB = [&](int b, int nh, int kt) {
        const int k0 = kt << 6;
        #pragma unroll
        for (int i = 0; i < 2; ++i) {
            const unsigned ru  = (unsigned)(i*64) + (t >> 3);       // 0..127
            const unsigned row = (ru >> 5)*64 + nh*32 + (ru & 31);  // B tile row
            const unsigned cb  = (t & 7) << 4;
            const unsigned scb = cb ^ ((row & 7) << 4);
            llds16(Bw + (size_t)(bcol + row) * K + (k0 + (scb >> 1)),
                   &lds[b][16384] + (((row << 7) + cb) >> 1));
        }
    };

    f32x4 acc[8][4] = {};
    bf16x8 af[4][2], bfv[2][2];

    auto rdA = [&](int b, int mh) {
        const char* base = (const char*)&lds[b][0];
        #pragma unroll
        for (int m = 0; m < 4; ++m)
            #pragma unroll
            for (int ks = 0; ks < 2; ++ks) {
                const unsigned row = wm*128 + mh*64 + m*16 + lr;
                af[m][ks] = *(const bf16x8*)(base + (row << 7) +
                    (((unsigned)(ks*64 + lhi*16)) ^ ((row & 7) << 4)));
            }
    };
    auto rdB = [&](int b, int nh) {
        const char* base = (const char*)&lds[b][16384];
        #pragma unroll
        for (int n = 0; n < 2; ++n)
            #pragma unroll
            for (int ks = 0; ks < 2; ++ks) {
                const unsigned row = wn*64 + nh*32 + n*16 + lr;
                bfv[n][ks] = *(const bf16x8*)(base + (row << 7) +
                    (((unsigned)(ks*64 + lhi*16)) ^ ((row & 7) << 4)));
            }
    };

#define MFMA16(MH, NH) do { \
    __builtin_amdgcn_s_setprio(1); \
    _Pragma("unroll") \
    for (int m = 0; m < 4; ++m) \
        _Pragma("unroll") \
        for (int n = 0; n < 2; ++n) \
            _Pragma("unroll") \
            for (int ks = 0; ks < 2; ++ks) \
                acc[(MH)*4+m][(NH)*2+n] = __builtin_amdgcn_mfma_f32_16x16x32_bf16( \
                    af[m][ks], bfv[n][ks], acc[(MH)*4+m][(NH)*2+n], 0, 0, 0); \
    __builtin_amdgcn_s_setprio(0); \
} while (0)

    const int nkt = K >> 6;                 // 32 K-tiles
    // prologue: buf0 full (kt0), buf1 A0+B0 (kt1)
    stgA(0, 0, 0); stgA(0, 1, 0); stgB(0, 0, 0); stgB(0, 1, 0);
    stgA(1, 0, 1); stgB(1, 0, 1);
    asm volatile("s_waitcnt vmcnt(4)" ::: "memory");
    BAR();

    for (int it = 0; it < nkt/2; ++it) {
        const int kt0 = 2*it, kt1 = 2*it + 1;
        const bool s02 = (kt0 + 2 < nkt), s12 = (kt1 + 2 < nkt);
        // ph1: q(0,0)@buf0; stage buf1.A1 <- kt1
        rdA(0, 0); rdB(0, 0);
        stgA(1, 1, kt1);
        BAR(); LGKM0(); MFMA16(0, 0); BAR();
        // ph2: q(0,1)@buf0; stage buf1.B1 <- kt1
        rdB(0, 1);
        stgB(1, 1, kt1);
        BAR(); LGKM0(); MFMA16(0, 1); BAR();
        // ph3: q(1,0)@buf0; stage buf0.A0 <- kt0+2
        rdA(0, 1); rdB(0, 0);
        if (s02) stgA(0, 0, kt0 + 2);
        BAR(); LGKM0(); MFMA16(1, 0); BAR();
        // ph4: q(1,1)@buf0; stage buf0.B0 <- kt0+2; vmcnt
        rdB(0, 1);
        if (s02) stgB(0, 0, kt0 + 2);
        BAR(); LGKM0(); MFMA16(1, 1);
        if (s02) { asm volatile("s_waitcnt vmcnt(4)" ::: "memory"); }
        else     { asm volatile("s_waitcnt vmcnt(0)" ::: "memory"); }
        BAR();
        // ph5: q(0,0)@buf1; stage buf0.A1 <- kt0+2
        rdA(1, 0); rdB(1, 0);
        if (s02) stgA(0, 1, kt0 + 2);
        BAR(); LGKM0(); MFMA16(0, 0); BAR();
        // ph6: q(0,1)@buf1; stage buf0.B1 <- kt0+2
        rdB(1, 1);
        if (s02) stgB(0, 1, kt0 + 2);
        BAR(); LGKM0(); MFMA16(0, 1); BAR();
        // ph7: q(1,0)@buf1; stage buf1.A0 <- kt1+2
        rdA(1, 1); rdB(1, 0);
        if (s12) stgA(1, 0, kt1 + 2);
        BAR(); LGKM0(); MFMA16(1, 0); BAR();
        // ph8: q(1,1)@buf1; stage buf1.B0 <- kt1+2; vmcnt(4)
        rdB(1, 1);
        if (s12) stgB(1, 0, kt1 + 2);
        BAR(); LGKM0(); MFMA16(1, 1);
        asm volatile("s_waitcnt vmcnt(4)" ::: "memory");
        BAR();
    }
#undef MFMA16

    // epilogue: wave owns rows [brow+wm*128, +128), cols [bcol+wn*64, +64)
    const int rowb = brow + wm*128;
    const int c64 = bcol + wn*64;
    const int hb  = c64 >> 6;               // 0..47: <32 Q, <40 K, else V
    if (hb < 40) {
        const bool isQ = hb < 32;
        const float sc = isQ ? (0.125f * LOG2E * kw[hb]) : 1.0f;
        u16* dst = isQ ? qpk : kpk;
        const int nheads = isQ ? 32 : 8;
        const int hloc = isQ ? hb : (hb - 32);
        #pragma unroll
        for (int nn = 0; nn < 2; ++nn) {
            const int i = nn*16 + lr;
            const float b1 = bias[c64 + i];
            const float b2 = bias[c64 + i + 32];
            #pragma unroll
            for (int mf = 0; mf < 8; ++mf) {
                #pragma unroll
                for (int j = 0; j < 4; ++j) {
                    const int row = rowb + mf*16 + lhi*4 + j;
                    const int s = row & (S_LEN - 1);
                    const int bb = row >> 11;
                    const float x1 = acc[mf][nn][j] + b1;
                    const float x2 = acc[mf][nn+2][j] + b2;
                    const float cs = rtab[s*32 + i];
                    const float sn = rtab[S_LEN*32 + s*32 + i];
                    const size_t base = ((size_t)(bb*nheads + hloc)) * (S_LEN*64) + (size_t)s*64;
                    dst[base + i]      = f2bf((x1*cs - x2*sn) * sc);
                    dst[base + i + 32] = f2bf((x2*cs + x1*sn) * sc);
                }
            }
        }
    } else {
        #pragma unroll
        for (int nn = 0; nn < 4; ++nn) {
            const int col = c64 + nn*16 + lr;
            const float bv = bias[col];
            #pragma unroll
            for (int mf = 0; mf < 8; ++mf)
                #pragma unroll
                for (int j = 0; j < 4; ++j) {
                    const int row = rowb + mf*16 + lhi*4 + j;
                    vlin[(size_t)row * 512 + (col - 2560)] = f2bf(acc[mf][nn][j] + bv);
                }
        }
    }
}

// ---------------- o-proj GEMM (R15 2-phase structure, unchanged) ----------------
__global__ __launch_bounds__(256, 2) void gemm_bt(
    const u16* __restrict__ A, const u16* __restrict__ Bw,
    const float* __restrict__ bias, float* __restrict__ C,
    int M, int N, int K)
{
    const int nbn = N >> 8;
    const int nwg = (M >> 7) * nbn;
    int wg = blockIdx.x;
    wg = (wg & 7) * (nwg >> 3) + (wg >> 3);
    const int bm = wg / nbn, bn = wg % nbn;
    const int brow = bm << 7, bcol = bn << 8;

    __shared__ u16 sbuf[3][12288];

    const int t = threadIdx.x;
    const int lane = t & 63, wid = t >> 6;
    const int wr = wid >> 1, wn = wid & 1;
    const int lr = lane & 15, lhi = lane >> 4;

    auto stageA = [&](int kt, int bi) {
        const int k0 = kt << 5;
        #pragma unroll
        for (int i = 0; i < 2; ++i) {
            const unsigned off = ((unsigned)t << 4) + ((unsigned)i << 12);
            const unsigned row = off >> 6;
            const unsigned scb = (off & 63) ^ swz(row);
            llds16(A + (size_t)(brow + row) * K + (k0 + (scb >> 1)), &sbuf[bi][0] + (off >> 1));
        }
        {
            const unsigned off = ((unsigned)t << 4);
            const unsigned row = off >> 6;
            const unsigned scb = (off & 63) ^ swz(row);
            llds16(Bw + (size_t)(bcol + row) * K + (k0 + (scb >> 1)), &sbuf[bi][4096] + (off >> 1));
        }
    };
    auto stageB = [&](int kt, int bi) {
        const int k0 = kt << 5;
        #pragma unroll
        for (int i = 1; i < 4; ++i) {
            const unsigned off = ((unsigned)t << 4) + ((unsigned)i << 12);
            const unsigned row = off >> 6;
            const unsigned scb = (off & 63) ^ swz(row);
            llds16(Bw + (size_t)(bcol + row) * K + (k0 + (scb >> 1)), &sbuf[bi][4096] + (off >> 1));
        }
    };

    f32x4 acc[4][8] = {};
    const int nk = K >> 5;

    stageA(0, 0); stageB(0, 0);
    stageA(1, 1); stageB(1, 1);
    asm volatile("s_waitcnt vmcnt(6)" ::: "memory");
    BAR();

    int cur = 0, st2 = 2;
    for (int kt = 0; kt < nk; ++kt) {
        const char* sA = (const char*)&sbuf[cur][0];
        const char* sB = (const char*)&sbuf[cur][4096];
        bf16x8 af[4], bfv[8];
        #pragma unroll
        for (int m = 0; m < 4; ++m) {
            const unsigned row = wr*64 + m*16 + lr;
            af[m] = *(const bf16x8*)(sA + row*64 + ((unsigned)(lhi*16) ^ swz(row)));
        }
        #pragma unroll
        for (int n = 0; n < 4; ++n) {
            const unsigned row = wn*128 + n*16 + lr;
            bfv[n] = *(const bf16x8*)(sB + row*64 + ((unsigned)(lhi*16) ^ swz(row)));
        }
        if (kt + 2 < nk) stageA(kt + 2, st2);
        BAR();
        LGKM0();
        __builtin_amdgcn_s_setprio(1);
        #pragma unroll
        for (int m = 0; m < 4; ++m)
            #pragma unroll
            for (int n = 0; n < 4; ++n)
                acc[m][n] = __builtin_amdgcn_mfma_f32_16x16x32_bf16(af[m], bfv[n], acc[m][n], 0, 0, 0);
        __builtin_amdgcn_s_setprio(0);
        BAR();
        #pragma unroll
        for (int n = 4; n < 8; ++n) {
            const unsigned row = wn*128 + n*16 + lr;
            bfv[n] = *(const bf16x8*)(sB + row*64 + ((unsigned)(lhi*16) ^ swz(row)));
        }
        if (kt + 2 < nk) stageB(kt + 2, st2);
        BAR();
        LGKM0();
        __builtin_amdgcn_s_setprio(1);
        #pragma unroll
        for (int m = 0; m < 4; ++m)
            #pragma unroll
            for (int n = 4; n < 8; ++n)
                acc[m][n] = __builtin_amdgcn_mfma_f32_16x16x32_bf16(af[m], bfv[n], acc[m][n], 0, 0, 0);
        __builtin_amdgcn_s_setprio(0);
        if (kt + 2 < nk) {
            asm volatile("s_waitcnt vmcnt(6)" ::: "memory");
            BAR();
        } else if (kt + 1 < nk) {
            asm volatile("s_waitcnt vmcnt(0)" ::: "memory");
            BAR();
        }
        cur = (cur == 2) ? 0 : cur + 1;
        st2 = (st2 == 2) ? 0 : st2 + 1;
    }

    #pragma unroll
    for (int m = 0; m < 4; ++m) {
        #pragma unroll
        for (int n = 0; n < 8; ++n) {
            const int col = bcol + wn*128 + n*16 + lr;
            const float bv = bias[col];
            #pragma unroll
            for (int j = 0; j < 4; ++j) {
                const int row = brow + wr*64 + m*16 + lhi*4 + j;
                C[(size_t)row * N + col] = acc[m][n][j] + bv;
            }
        }
    }
}

// ---------------- pack V transposed ----------------
__global__ void pack_vt(const u16* __restrict__ vlin, u16* __restrict__ vtb) {
    __shared__ u16 tile[64][67];
    const int st = blockIdx.x;
    const int bk = blockIdx.y;
    const int t = threadIdx.x;
    const int b = bk >> 3, kvh = bk & 7;
    const int r = t >> 2, cg = (t & 3) << 4;
    const u16* src = vlin + ((size_t)(b*S_LEN + st*64 + r)) * 512 + kvh*64 + cg;
    #pragma unroll
    for (int j = 0; j < 16; ++j) tile[r][cg + j] = src[j];
    __syncthreads();
    const int d = t >> 2, sg = (t & 3) << 4;
    u16* dst = vtb + ((size_t)(bk*64 + d)) * S_LEN + st*64 + sg;
    #pragma unroll
    for (int j = 0; j < 16; ++j) dst[j] = tile[sg + j][d];
}

// ---------------- flash attention (R15, unchanged) ----------------
__global__ __launch_bounds__(512, 4) void attn_fwd(
    const u16* __restrict__ Q,
    const u16* __restrict__ Kk,
    const u16* __restrict__ Vt,
    u16* __restrict__ O)
{
    __shared__ u16 sK[3][64 * 64];
    __shared__ u16 sV[3][64 * 64];

    const int t = threadIdx.x;
    const int lane = t & 63, wid = t >> 6;
    const int hi = lane >> 5, lq = lane & 31;
    const int bid = blockIdx.x;
    const int qb = (bid < 256) ? (7 - (bid >> 6)) : ((bid >> 6) - 4);
    const int bh = bid & 63;
    const int b = bh >> 5, h = bh & 31;
    const int kvh = h >> 2;

    const u16* Kp = Kk + ((size_t)(b*NKV + kvh)) * (S_LEN * 64);
    const u16* Vp = Vt + ((size_t)(b*NKV + kvh)) * (64 * S_LEN);

    const int q0w = qb*256 + wid*32;
    const int qg  = q0w + lq;

    const u16* Qrow = Q + (((size_t)bh) * S_LEN + qg) * 64 + 8*hi;
    bf16x8 qf[4];
    #pragma unroll
    for (int kd = 0; kd < 4; ++kd)
        qf[kd] = *(const bf16x8*)(Qrow + 16*kd);

    f32x16 accO0 = {}, accO1 = {};
    float m_run = 0.f, l_run = 0.f;

    const int ntB = 4*qb + 4;
    const int tmax_w = (q0w + 31) >> 6;

    auto stageKV = [&](int kt, int bi) {
        const int kv = kt << 6;
        const unsigned row = t >> 3, cb = (t & 7) << 4;
        const unsigned scb = cb ^ ((row & 7) << 4);
        llds16(Kp + (size_t)(kv + row) * 64 + (scb >> 1), &sK[bi][0] + t*8);
        llds16(Vp + (size_t)row * S_LEN + kv + (scb >> 1), &sV[bi][0] + t*8);
    };

    stageKV(0, 0);
    stageKV(1, 1);
    int cur = 0, st2 = 2;

    for (int tt = 0; tt < ntB; ++tt) {
        if (tt < ntB - 1) CBAR(2); else CBAR(0);
        if (tt + 2 < ntB) stageKV(tt + 2, st2);
        if (tt <= tmax_w) {
            const int kv0 = tt * 64;
            const float nm = -m_run;
            f32x16 s0, s1;
            #pragma unroll
            for (int r = 0; r < 16; ++r) { s0[r] = nm; s1[r] = nm; }
            __builtin_amdgcn_s_setprio(1);
            #pragma unroll
            for (int kd = 0; kd < 4; ++kd) {
                const unsigned bc = ((unsigned)(32*kd + 16*hi)) ^ ((lq & 7) << 4);
                bf16x8 k0 = *(const bf16x8*)((const char*)&sK[cur][0] + lq*128 + bc);
                bf16x8 k1 = *(const bf16x8*)((const char*)&sK[cur][0] + (32 + lq)*128 + bc);
                s0 = __builtin_amdgcn_mfma_f32_32x32x16_bf16(k0, qf[kd], s0, 0, 0, 0);
                s1 = __builtin_amdgcn_mfma_f32_32x32x16_bf16(k1, qf[kd], s1, 0, 0, 0);
            }
            __builtin_amdgcn_s_setprio(0);
            if (kv0 + 63 > q0w) {
                #pragma unroll
                for (int r = 0; r < 16; ++r) {
                    const int kvg = kv0 + (r & 3) + 8*(r >> 2) + 4*hi;
                    if (kvg > qg)      s0[r] = -INFINITY;
                    if (kvg + 32 > qg) s1[r] = -INFINITY;
                }
            }
            float mx[8];
            #pragma unroll
            for (int r = 0; r < 8; ++r)
                mx[r] = fmaxf(fmaxf(s0[r], s0[r+8]), fmaxf(s1[r], s1[r+8]));
            float tm = fmaxf(fmaxf(fmaxf(mx[0], mx[1]), fmaxf(mx[2], mx[3])),
                             fmaxf(fmaxf(mx[4], mx[5]), fmaxf(mx[6], mx[7])));
            tm = fmaxf(tm, __shfl_xor(tm, 32));
            if (!__all(tm <= 8.0f)) {
                const float dd = fmaxf(tm, 0.f);
                const float al = __builtin_amdgcn_exp2f(-dd);
                m_run += dd;
                l_run *= al;
                #pragma unroll
                for (int r = 0; r < 16; ++r) { accO0[r] *= al; accO1[r] *= al; }
                #pragma unroll
                for (int r = 0; r < 16; ++r) { s0[r] -= dd; s1[r] -= dd; }
            }
            #pragma unroll
            for (int r = 0; r < 16; ++r) {
                s0[r] = __builtin_amdgcn_exp2f(s0[r]);
                s1[r] = __builtin_amdgcn_exp2f(s1[r]);
            }
            float sm[8];
            #pragma unroll
            for (int r = 0; r < 8; ++r)
                sm[r] = (s0[r] + s0[r+8]) + (s1[r] + s1[r+8]);
            float rs = ((sm[0]+sm[1]) + (sm[2]+sm[3])) + ((sm[4]+sm[5]) + (sm[6]+sm[7]));
            rs += __shfl_xor(rs, 32);
            l_run += rs;

            #pragma unroll
            for (int ks = 0; ks < 4; ++ks) {
                const f32x16& e = (ks & 2) ? s1 : s0;
                const int rb = (ks & 1) * 8;
                unsigned x0 = cvtpk(e[rb + 0], e[rb + 1]);
                unsigned x1 = cvtpk(e[rb + 2], e[rb + 3]);
                unsigned y0 = cvtpk(e[rb + 4], e[rb + 5]);
                unsigned y1 = cvtpk(e[rb + 6], e[rb + 7]);
                plswap(x0, y0);
                plswap(x1, y1);
                union { unsigned u[4]; bf16x8 v; } pb;
                pb.u[0] = x0; pb.u[1] = x1; pb.u[2] = y0; pb.u[3] = y1;
                const unsigned bc = ((unsigned)(32*ks + 16*hi)) ^ ((lq & 7) << 4);
                bf16x8 v0 = *(const bf16x8*)((const char*)&sV[cur][0] + lq*128 + bc);
                bf16x8 v1 = *(const bf16x8*)((const char*)&sV[cur][0] + (32 + lq)*128 + bc);
                __builtin_amdgcn_s_setprio(1);
                accO0 = __builtin_amdgcn_mfma_f32_32x32x16_bf16(v0, pb.v, accO0, 0, 0, 0);
                accO1 = __builtin_amdgcn_mfma_f32_32x32x16_bf16(v1, pb.v, accO1, 0, 0, 0);
                __builtin_amdgcn_s_setprio(0);
            }
        }
        cur = (cur == 2) ? 0 : cur + 1;
        st2 = (st2 == 2) ? 0 : st2 + 1;
    }

    const float inv = 1.0f / l_run;
    u16* orow = O + (((size_t)(b * S_LEN) + q0w + lq)) * (NH*HD) + h*64;
    #pragma unroll
    for (int g = 0; g < 4; ++g) {
        uint2 w0, w1;
        w0.x = cvtpk(accO0[4*g + 0] * inv, accO0[4*g + 1] * inv);
        w0.y = cvtpk(accO0[4*g + 2] * inv, accO0[4*g + 3] * inv);
        *(uint2*)(orow + 8*g + 4*hi) = w0;
        w1.x = cvtpk(accO1[4*g + 0] * inv, accO1[4*g + 1] * inv);
        w1.y = cvtpk(accO1[4*g + 2] * inv, accO1[4*g + 3] * inv);
        *(uint2*)(orow + 32 + 8*g + 4*hi) = w1;
    }
}

// ---------------- host launcher ----------------
extern "C" void kernel_launch(void* const* d_in, const int* in_sizes, int n_in,
                              void* d_out, int out_size, void* d_ws, size_t ws_size,
                              hipStream_t stream) {
    const float* x  = (const float*)d_in[0];
    const float* Wq = (const float*)d_in[1];
    const float* bq = (const float*)d_in[2];
    const float* Wk = (const float*)d_in[3];
    const float* bk = (const float*)d_in[4];
    const float* Wv = (const float*)d_in[5];
    const float* bv = (const float*)d_in[6];
    const float* Wo = (const float*)d_in[7];
    const float* bo = (const float*)d_in[8];
    const float* kw = (const float*)d_in[9];

    uint8_t* ws = (uint8_t*)d_ws;
    u16*   xb    = (u16*)(ws);                    // 16 MiB
    u16*   wqkvb = (u16*)(ws + 16777216);         // 12 MiB
    u16*   wob   = (u16*)(ws + 29360128);         //  8 MiB
    u16*   qpk   = (u16*)(ws + 37748736);         // 16 MiB
    u16*   kpk   = (u16*)(ws + 54525952);         //  4 MiB
    u16*   vlin  = (u16*)(ws + 58720256);         //  4 MiB
    u16*   vtb   = (u16*)(ws + 62914560);         //  4 MiB
    u16*   ob    = (u16*)(ws + 67108864);         // 16 MiB
    float* bqkv  = (float*)(ws + 83886080);       // 12 KiB
    float* rtab  = (float*)(ws + 83898368);       // 512 KiB

    prep_all<<<9484, 256, 0, stream>>>(x, Wq, Wk, Wv, Wo, bq, bk, bv,
                                       xb, wqkvb, wob, rtab, bqkv);

    // 8-phase 256^2 QKV GEMM: 192 blocks x 512 threads
    gemm_qkv<<<192, 512, 0, stream>>>(xb, wqkvb, bqkv, rtab, kw, qpk, kpk, vlin);

    pack_vt<<<dim3(32, 16), 256, 0, stream>>>(vlin, vtb);

    attn_fwd<<<dim3(512), dim3(512), 0, stream>>>(qpk, kpk, vtb, ob);

    gemm_bt<<<256, 256, 0, stream>>>(ob, wob, bo, (float*)d_out, NROWS, HID, HID);

    (void)in_sizes; (void)n_in; (void)out_size; (void)ws_size;
}